// Round 4
// baseline (423.668 us; speedup 1.0000x reference)
//
#include <hip/hip_runtime.h>
#include <hip/hip_bf16.h>
#include <cstdint>

#define B_ 2
#define T_ 2048
#define D_ 512
#define H_ 8
#define DK_ 64
#define TQ_ 4
#define NT_ (T_ / TQ_)   // 512 tiles of 4 rows
#define M_ (B_ * T_)     // 4096

// ---------------- GEMM: C[M,N] = A[M,K] @ W[K,N] + bias[N] ----------------
__global__ __launch_bounds__(256) void gemm_bias_kernel(
    const float* __restrict__ A, const float* __restrict__ W,
    const float* __restrict__ bias, float* __restrict__ C,
    int M, int N, int K)
{
  __shared__ float As[16][68];  // transposed A tile: As[k][m]
  __shared__ float Bs[16][68];
  const int bm = blockIdx.y * 64;
  const int bn = blockIdx.x * 64;
  const int tid = threadIdx.x;
  const int tx = tid & 15, ty = tid >> 4;
  float acc[4][4] = {};
  for (int k0 = 0; k0 < K; k0 += 16) {
    {
      const int r = tid >> 2;           // 0..63
      const int c = (tid & 3) << 2;     // 0,4,8,12
      const float4 a = *reinterpret_cast<const float4*>(&A[(size_t)(bm + r) * K + k0 + c]);
      As[c + 0][r] = a.x; As[c + 1][r] = a.y; As[c + 2][r] = a.z; As[c + 3][r] = a.w;
    }
    {
      const int r = tid >> 4;           // 0..15
      const int c = (tid & 15) << 2;    // 0..60
      *reinterpret_cast<float4*>(&Bs[r][c]) =
          *reinterpret_cast<const float4*>(&W[(size_t)(k0 + r) * N + bn + c]);
    }
    __syncthreads();
#pragma unroll
    for (int kk = 0; kk < 16; ++kk) {
      float av[4], bv[4];
#pragma unroll
      for (int i = 0; i < 4; ++i) av[i] = As[kk][ty * 4 + i];
#pragma unroll
      for (int j = 0; j < 4; ++j) bv[j] = Bs[kk][tx * 4 + j];
#pragma unroll
      for (int i = 0; i < 4; ++i)
#pragma unroll
        for (int j = 0; j < 4; ++j) acc[i][j] += av[i] * bv[j];
    }
    __syncthreads();
  }
#pragma unroll
  for (int i = 0; i < 4; ++i) {
    const int row = bm + ty * 4 + i;
#pragma unroll
    for (int j = 0; j < 4; ++j) {
      const int col = bn + tx * 4 + j;
      C[(size_t)row * N + col] = acc[i][j] + bias[col];
    }
  }
}

// Same GEMM but writes C TRANSPOSED: Ct[N][M].
__global__ __launch_bounds__(256) void gemm_bias_kernelT(
    const float* __restrict__ A, const float* __restrict__ W,
    const float* __restrict__ bias, float* __restrict__ Ct,
    int M, int N, int K)
{
  __shared__ float As[16][68];
  __shared__ float Bs[16][68];
  const int bm = blockIdx.y * 64;
  const int bn = blockIdx.x * 64;
  const int tid = threadIdx.x;
  const int tx = tid & 15, ty = tid >> 4;
  float acc[4][4] = {};
  for (int k0 = 0; k0 < K; k0 += 16) {
    {
      const int r = tid >> 2;
      const int c = (tid & 3) << 2;
      const float4 a = *reinterpret_cast<const float4*>(&A[(size_t)(bm + r) * K + k0 + c]);
      As[c + 0][r] = a.x; As[c + 1][r] = a.y; As[c + 2][r] = a.z; As[c + 3][r] = a.w;
    }
    {
      const int r = tid >> 4;
      const int c = (tid & 15) << 2;
      *reinterpret_cast<float4*>(&Bs[r][c]) =
          *reinterpret_cast<const float4*>(&W[(size_t)(k0 + r) * N + bn + c]);
    }
    __syncthreads();
#pragma unroll
    for (int kk = 0; kk < 16; ++kk) {
      float av[4], bv[4];
#pragma unroll
      for (int i = 0; i < 4; ++i) av[i] = As[kk][ty * 4 + i];
#pragma unroll
      for (int j = 0; j < 4; ++j) bv[j] = Bs[kk][tx * 4 + j];
#pragma unroll
      for (int i = 0; i < 4; ++i)
#pragma unroll
        for (int j = 0; j < 4; ++j) acc[i][j] += av[i] * bv[j];
    }
    __syncthreads();
  }
#pragma unroll
  for (int j = 0; j < 4; ++j) {
    const int col = bn + tx * 4 + j;
    const float bb = bias[col];
    const float4 v = make_float4(acc[0][j] + bb, acc[1][j] + bb, acc[2][j] + bb, acc[3][j] + bb);
    *reinterpret_cast<float4*>(&Ct[(size_t)col * M + bm + ty * 4]) = v;
  }
}

// ---------------- V_combined = mean over heads of V ----------------
__global__ __launch_bounds__(256) void vcombine_kernel(const float* __restrict__ V,
                                                       float* __restrict__ Vc)
{
  const int idx = blockIdx.x * 256 + threadIdx.x;
  if (idx >= M_ * DK_) return;
  const int row = idx >> 6, d = idx & 63;
  float s = 0.f;
#pragma unroll
  for (int h = 0; h < H_; ++h) s += V[(size_t)row * D_ + h * DK_ + d];
  Vc[idx] = s * 0.125f;
}

// ---------------- fused causal scores + 1.5-entmax (in-register Newton) ----------------
__global__ __launch_bounds__(256, 4) void attn_kernel(
    const float* __restrict__ Qg, const float* __restrict__ Kt,
    const float* __restrict__ Vc, float* __restrict__ wavg,
    float* __restrict__ attn_out)
{
  __shared__ float sc[TQ_][T_];        // 32 KB: scores for current head; reused as wsum at end
  __shared__ float4 qs4[TQ_][16];      // 1 KB
  __shared__ float part[4][TQ_][DK_];  // 4 KB

  const int tid = threadIdx.x;
  const int b = blockIdx.x & 1;
  const int tile = (NT_ - 1) - (blockIdx.x >> 1);  // heavy tiles first
  const int t0 = tile * TQ_;
  const int nS = t0 + TQ_;             // needed s range [0, nS)
  const int wave = tid >> 6;
  const int lane = tid & 63;
  const int n = t0 + wave + 1;         // support upper bound for this wave's row

  float wacc[32];                      // head-accumulated entmax weights (reg)
#pragma unroll
  for (int j = 0; j < 32; ++j) wacc[j] = 0.f;

  for (int h = 0; h < H_; ++h) {
    __syncthreads();  // all waves consumed sc of previous head
    if (tid < TQ_ * 16) {
      const int r = tid >> 4, d4 = tid & 15;
      qs4[r][d4] = *reinterpret_cast<const float4*>(
          &Qg[(size_t)(b * T_ + t0 + r) * D_ + h * DK_ + d4 * 4]);
    }
    __syncthreads();

    // scores: z[r][s] = (Q[t0+r] . K[s]) * 0.0625, s < nS.
    for (int s0 = tid * 4; s0 < nS; s0 += 1024) {
      const float* Ktp = &Kt[(size_t)(h * DK_) * M_ + b * T_ + s0];
      float4 acc0 = {}, acc1 = {}, acc2 = {}, acc3 = {};
#pragma unroll 4
      for (int d4 = 0; d4 < 16; ++d4) {
        const float4 q0 = qs4[0][d4];  // LDS same-address broadcast (free)
        const float4 q1 = qs4[1][d4];
        const float4 q2 = qs4[2][d4];
        const float4 q3 = qs4[3][d4];
        const float4 k0 = *reinterpret_cast<const float4*>(Ktp + (size_t)(d4 * 4 + 0) * M_);
        const float4 k1 = *reinterpret_cast<const float4*>(Ktp + (size_t)(d4 * 4 + 1) * M_);
        const float4 k2 = *reinterpret_cast<const float4*>(Ktp + (size_t)(d4 * 4 + 2) * M_);
        const float4 k3 = *reinterpret_cast<const float4*>(Ktp + (size_t)(d4 * 4 + 3) * M_);
#define FMA4(a, qv, kv) a.x = fmaf(qv, kv.x, a.x); a.y = fmaf(qv, kv.y, a.y); \
                        a.z = fmaf(qv, kv.z, a.z); a.w = fmaf(qv, kv.w, a.w)
        FMA4(acc0, q0.x, k0); FMA4(acc0, q0.y, k1); FMA4(acc0, q0.z, k2); FMA4(acc0, q0.w, k3);
        FMA4(acc1, q1.x, k0); FMA4(acc1, q1.y, k1); FMA4(acc1, q1.z, k2); FMA4(acc1, q1.w, k3);
        FMA4(acc2, q2.x, k0); FMA4(acc2, q2.y, k1); FMA4(acc2, q2.z, k2); FMA4(acc2, q2.w, k3);
        FMA4(acc3, q3.x, k0); FMA4(acc3, q3.y, k1); FMA4(acc3, q3.z, k2); FMA4(acc3, q3.w, k3);
#undef FMA4
      }
      acc0.x *= 0.0625f; acc0.y *= 0.0625f; acc0.z *= 0.0625f; acc0.w *= 0.0625f;
      acc1.x *= 0.0625f; acc1.y *= 0.0625f; acc1.z *= 0.0625f; acc1.w *= 0.0625f;
      acc2.x *= 0.0625f; acc2.y *= 0.0625f; acc2.z *= 0.0625f; acc2.w *= 0.0625f;
      acc3.x *= 0.0625f; acc3.y *= 0.0625f; acc3.z *= 0.0625f; acc3.w *= 0.0625f;
      *reinterpret_cast<float4*>(&sc[0][s0]) = acc0;
      *reinterpret_cast<float4*>(&sc[1][s0]) = acc1;
      *reinterpret_cast<float4*>(&sc[2][s0]) = acc2;
      *reinterpret_cast<float4*>(&sc[3][s0]) = acc3;
    }
    __syncthreads();

    // wave r: pull its row into registers (lane-stride 4B, conflict-free)
    float srow[32];
#pragma unroll
    for (int j = 0; j < 32; ++j) {
      if (j * 64 < n) {                       // wave-uniform -> scalar branch
        const int s = lane + j * 64;
        const float v = sc[wave][s];
        srow[j] = (s < n) ? v : -1e30f;       // mask causal tail within chunk
      }
    }

    // max reduce
    float mx = -1e30f;
#pragma unroll
    for (int j = 0; j < 32; ++j)
      if (j * 64 < n) mx = fmaxf(mx, srow[j]);
#pragma unroll
    for (int m = 32; m >= 1; m >>= 1) mx = fmaxf(mx, __shfl_xor(mx, m, 64));

    // Newton on f(tau) = sum max(z-tau,0)^2 - 1 (convex, decreasing).
    // tau0 = mx-1 gives f>=0; iterates increase monotonically to tau*.
    // Break on function value: s2-1 < 1e-5 bounds the weight error at 1e-5.
    float tau = mx - 1.0f;
#pragma unroll 1
    for (int it = 0; it < 16; ++it) {
      float s1 = 0.f, s2 = 0.f;
#pragma unroll
      for (int j = 0; j < 32; ++j) {
        if (j * 64 < n) {
          const float u = fmaxf(srow[j] - tau, 0.f);
          s1 += u;
          s2 = fmaf(u, u, s2);
        }
      }
#pragma unroll
      for (int m = 32; m >= 1; m >>= 1) {
        s1 += __shfl_xor(s1, m, 64);
        s2 += __shfl_xor(s2, m, 64);
      }
      if (s2 - 1.0f < 1e-5f) break;  // wave-uniform (s2 fully reduced)
      tau += (s2 - 1.0f) / fmaxf(2.f * s1, 1e-12f);
    }
    tau = fminf(tau, mx - 1e-8f);

    // accumulate weights for this head
#pragma unroll
    for (int j = 0; j < 32; ++j) {
      if (j * 64 < n) {
        const float u = fmaxf(srow[j] - tau, 0.f);
        wacc[j] = fmaf(u, u, wacc[j]);
      }
    }
  }
  __syncthreads();  // sc free for reuse as wsum

  // dump register weights to LDS (full row; untouched chunks are zero)
#pragma unroll
  for (int j = 0; j < 32; ++j) sc[wave][lane + j * 64] = wacc[j];
  __syncthreads();

  // weights_avg: coalesced float4 stores, full T row (zeros past diagonal required)
  for (int i4 = tid; i4 < TQ_ * T_ / 4; i4 += 256) {
    const int r = i4 >> 9;                 // / (T_/4)
    const int c4 = i4 & 511;
    float4 w = reinterpret_cast<const float4*>(&sc[r][0])[c4];
    w.x *= 0.125f; w.y *= 0.125f; w.z *= 0.125f; w.w *= 0.125f;
    reinterpret_cast<float4*>(&wavg[(size_t)(b * T_ + t0 + r) * T_])[c4] = w;
  }

  // PV: attn_out[t0+r][d] = 0.125 * sum_s wsum[r][s] * Vc[s][d]
  {
    const int sg = tid >> 6, dd = tid & 63;
    float acc0 = 0.f, acc1 = 0.f, acc2 = 0.f, acc3 = 0.f;
    for (int s = sg; s < nS; s += 4) {
      const float v = Vc[(size_t)(b * T_ + s) * DK_ + dd];
      acc0 += sc[0][s] * v;
      acc1 += sc[1][s] * v;
      acc2 += sc[2][s] * v;
      acc3 += sc[3][s] * v;
    }
    part[sg][0][dd] = acc0;
    part[sg][1][dd] = acc1;
    part[sg][2][dd] = acc2;
    part[sg][3][dd] = acc3;
  }
  __syncthreads();
  {
    const int r = tid >> 6, dd = tid & 63;
    const float o = (part[0][r][dd] + part[1][r][dd] + part[2][r][dd] + part[3][r][dd]) * 0.125f;
    attn_out[(size_t)(b * T_ + t0 + r) * DK_ + dd] = o;
  }
}

extern "C" void kernel_launch(void* const* d_in, const int* in_sizes, int n_in,
                              void* d_out, int out_size, void* d_ws, size_t ws_size,
                              hipStream_t stream)
{
  const float* x  = (const float*)d_in[0];
  const float* Wq = (const float*)d_in[1];
  const float* bq = (const float*)d_in[2];
  const float* Wk = (const float*)d_in[3];
  const float* bk = (const float*)d_in[4];
  const float* Wv = (const float*)d_in[5];
  const float* bv = (const float*)d_in[6];
  const float* Wo = (const float*)d_in[7];
  const float* bo = (const float*)d_in[8];
  float* out = (float*)d_out;
  float* ws  = (float*)d_ws;

  float* Q  = ws;                        // [M,512]
  float* Kt = Q + (size_t)M_ * D_;       // [512,M]
  float* V  = Kt + (size_t)D_ * M_;      // [M,512]
  float* Vc = V + (size_t)M_ * D_;       // [M,64]
  float* AO = Vc + (size_t)M_ * DK_;     // [M,64]

  float* out1 = out;                    // [B,T,D]
  float* wavg = out + (size_t)M_ * D_;  // [B,T,T]

  const dim3 gp(D_ / 64, M_ / 64);  // (8, 64)
  gemm_bias_kernel <<<gp, 256, 0, stream>>>(x, Wq, bq, Q,  M_, D_, D_);
  gemm_bias_kernelT<<<gp, 256, 0, stream>>>(x, Wk, bk, Kt, M_, D_, D_);
  gemm_bias_kernel <<<gp, 256, 0, stream>>>(x, Wv, bv, V,  M_, D_, D_);
  vcombine_kernel<<<(M_ * DK_ + 255) / 256, 256, 0, stream>>>(V, Vc);
  attn_kernel<<<B_ * NT_, 256, 0, stream>>>(Q, Kt, Vc, wavg, AO);
  gemm_bias_kernel<<<gp, 256, 0, stream>>>(AO, Wo, bo, out1, M_, D_, DK_);
}

// Round 5
// 405.224 us; speedup vs baseline: 1.0455x; 1.0455x over previous
//
#include <hip/hip_runtime.h>
#include <hip/hip_bf16.h>
#include <cstdint>

#define B_ 2
#define T_ 2048
#define D_ 512
#define H_ 8
#define DK_ 64
#define TQ_ 4
#define NT_ (T_ / TQ_)   // 512 tiles of 4 rows
#define M_ (B_ * T_)     // 4096

// ---------------- GEMM: C[M,N] = A[M,K] @ W[K,N] + bias[N] ----------------
__global__ __launch_bounds__(256) void gemm_bias_kernel(
    const float* __restrict__ A, const float* __restrict__ W,
    const float* __restrict__ bias, float* __restrict__ C,
    int M, int N, int K)
{
  __shared__ float As[16][68];  // transposed A tile: As[k][m]
  __shared__ float Bs[16][68];
  const int bm = blockIdx.y * 64;
  const int bn = blockIdx.x * 64;
  const int tid = threadIdx.x;
  const int tx = tid & 15, ty = tid >> 4;
  float acc[4][4] = {};
  for (int k0 = 0; k0 < K; k0 += 16) {
    {
      const int r = tid >> 2;           // 0..63
      const int c = (tid & 3) << 2;     // 0,4,8,12
      const float4 a = *reinterpret_cast<const float4*>(&A[(size_t)(bm + r) * K + k0 + c]);
      As[c + 0][r] = a.x; As[c + 1][r] = a.y; As[c + 2][r] = a.z; As[c + 3][r] = a.w;
    }
    {
      const int r = tid >> 4;           // 0..15
      const int c = (tid & 15) << 2;    // 0..60
      *reinterpret_cast<float4*>(&Bs[r][c]) =
          *reinterpret_cast<const float4*>(&W[(size_t)(k0 + r) * N + bn + c]);
    }
    __syncthreads();
#pragma unroll
    for (int kk = 0; kk < 16; ++kk) {
      float av[4], bv[4];
#pragma unroll
      for (int i = 0; i < 4; ++i) av[i] = As[kk][ty * 4 + i];
#pragma unroll
      for (int j = 0; j < 4; ++j) bv[j] = Bs[kk][tx * 4 + j];
#pragma unroll
      for (int i = 0; i < 4; ++i)
#pragma unroll
        for (int j = 0; j < 4; ++j) acc[i][j] += av[i] * bv[j];
    }
    __syncthreads();
  }
#pragma unroll
  for (int i = 0; i < 4; ++i) {
    const int row = bm + ty * 4 + i;
#pragma unroll
    for (int j = 0; j < 4; ++j) {
      const int col = bn + tx * 4 + j;
      C[(size_t)row * N + col] = acc[i][j] + bias[col];
    }
  }
}

// Same GEMM but writes C TRANSPOSED: Ct[N][M].
__global__ __launch_bounds__(256) void gemm_bias_kernelT(
    const float* __restrict__ A, const float* __restrict__ W,
    const float* __restrict__ bias, float* __restrict__ Ct,
    int M, int N, int K)
{
  __shared__ float As[16][68];
  __shared__ float Bs[16][68];
  const int bm = blockIdx.y * 64;
  const int bn = blockIdx.x * 64;
  const int tid = threadIdx.x;
  const int tx = tid & 15, ty = tid >> 4;
  float acc[4][4] = {};
  for (int k0 = 0; k0 < K; k0 += 16) {
    {
      const int r = tid >> 2;
      const int c = (tid & 3) << 2;
      const float4 a = *reinterpret_cast<const float4*>(&A[(size_t)(bm + r) * K + k0 + c]);
      As[c + 0][r] = a.x; As[c + 1][r] = a.y; As[c + 2][r] = a.z; As[c + 3][r] = a.w;
    }
    {
      const int r = tid >> 4;
      const int c = (tid & 15) << 2;
      *reinterpret_cast<float4*>(&Bs[r][c]) =
          *reinterpret_cast<const float4*>(&W[(size_t)(k0 + r) * N + bn + c]);
    }
    __syncthreads();
#pragma unroll
    for (int kk = 0; kk < 16; ++kk) {
      float av[4], bv[4];
#pragma unroll
      for (int i = 0; i < 4; ++i) av[i] = As[kk][ty * 4 + i];
#pragma unroll
      for (int j = 0; j < 4; ++j) bv[j] = Bs[kk][tx * 4 + j];
#pragma unroll
      for (int i = 0; i < 4; ++i)
#pragma unroll
        for (int j = 0; j < 4; ++j) acc[i][j] += av[i] * bv[j];
    }
    __syncthreads();
  }
#pragma unroll
  for (int j = 0; j < 4; ++j) {
    const int col = bn + tx * 4 + j;
    const float bb = bias[col];
    const float4 v = make_float4(acc[0][j] + bb, acc[1][j] + bb, acc[2][j] + bb, acc[3][j] + bb);
    *reinterpret_cast<float4*>(&Ct[(size_t)col * M + bm + ty * 4]) = v;
  }
}

// ---------------- V_combined = mean over heads of V ----------------
__global__ __launch_bounds__(256) void vcombine_kernel(const float* __restrict__ V,
                                                       float* __restrict__ Vc)
{
  const int idx = blockIdx.x * 256 + threadIdx.x;
  if (idx >= M_ * DK_) return;
  const int row = idx >> 6, d = idx & 63;
  float s = 0.f;
#pragma unroll
  for (int h = 0; h < H_; ++h) s += V[(size_t)row * D_ + h * DK_ + d];
  Vc[idx] = s * 0.125f;
}

// ---------------- fused causal scores + 1.5-entmax (in-register Newton) ----------------
// LDS caps occupancy at 4 blocks/CU = 4 waves/EU, so allow the full 128-VGPR
// budget (amdgpu_waves_per_eu(4,4)) -> srow[32]+wacc[32] stay in registers, no spill.
__global__ __launch_bounds__(256)
__attribute__((amdgpu_waves_per_eu(4, 4)))
void attn_kernel(
    const float* __restrict__ Qg, const float* __restrict__ Kt,
    const float* __restrict__ Vc, float* __restrict__ wavg,
    float* __restrict__ attn_out)
{
  __shared__ float sc[TQ_][T_];        // 32 KB: scores for current head; reused as wsum at end
  __shared__ float4 qs4[TQ_][16];      // 1 KB
  __shared__ float part[4][TQ_][DK_];  // 4 KB

  const int tid = threadIdx.x;
  const int b = blockIdx.x & 1;
  const int tile = (NT_ - 1) - (blockIdx.x >> 1);  // heavy tiles first
  const int t0 = tile * TQ_;
  const int nS = t0 + TQ_;             // needed s range [0, nS)
  const int wave = tid >> 6;
  const int lane = tid & 63;
  const int n = t0 + wave + 1;         // support upper bound for this wave's row

  float wacc[32];                      // head-accumulated entmax weights (reg)
#pragma unroll
  for (int j = 0; j < 32; ++j) wacc[j] = 0.f;

  for (int h = 0; h < H_; ++h) {
    __syncthreads();  // all waves consumed sc of previous head
    if (tid < TQ_ * 16) {
      const int r = tid >> 4, d4 = tid & 15;
      qs4[r][d4] = *reinterpret_cast<const float4*>(
          &Qg[(size_t)(b * T_ + t0 + r) * D_ + h * DK_ + d4 * 4]);
    }
    __syncthreads();

    // scores: z[r][s] = (Q[t0+r] . K[s]) * 0.0625, s < nS.
    for (int s0 = tid * 4; s0 < nS; s0 += 1024) {
      const float* Ktp = &Kt[(size_t)(h * DK_) * M_ + b * T_ + s0];
      float4 acc0 = {}, acc1 = {}, acc2 = {}, acc3 = {};
#pragma unroll 2
      for (int d4 = 0; d4 < 16; ++d4) {
        const float4 q0 = qs4[0][d4];  // LDS same-address broadcast (free)
        const float4 q1 = qs4[1][d4];
        const float4 q2 = qs4[2][d4];
        const float4 q3 = qs4[3][d4];
        const float4 k0 = *reinterpret_cast<const float4*>(Ktp + (size_t)(d4 * 4 + 0) * M_);
        const float4 k1 = *reinterpret_cast<const float4*>(Ktp + (size_t)(d4 * 4 + 1) * M_);
        const float4 k2 = *reinterpret_cast<const float4*>(Ktp + (size_t)(d4 * 4 + 2) * M_);
        const float4 k3 = *reinterpret_cast<const float4*>(Ktp + (size_t)(d4 * 4 + 3) * M_);
#define FMA4(a, qv, kv) a.x = fmaf(qv, kv.x, a.x); a.y = fmaf(qv, kv.y, a.y); \
                        a.z = fmaf(qv, kv.z, a.z); a.w = fmaf(qv, kv.w, a.w)
        FMA4(acc0, q0.x, k0); FMA4(acc0, q0.y, k1); FMA4(acc0, q0.z, k2); FMA4(acc0, q0.w, k3);
        FMA4(acc1, q1.x, k0); FMA4(acc1, q1.y, k1); FMA4(acc1, q1.z, k2); FMA4(acc1, q1.w, k3);
        FMA4(acc2, q2.x, k0); FMA4(acc2, q2.y, k1); FMA4(acc2, q2.z, k2); FMA4(acc2, q2.w, k3);
        FMA4(acc3, q3.x, k0); FMA4(acc3, q3.y, k1); FMA4(acc3, q3.z, k2); FMA4(acc3, q3.w, k3);
#undef FMA4
      }
      acc0.x *= 0.0625f; acc0.y *= 0.0625f; acc0.z *= 0.0625f; acc0.w *= 0.0625f;
      acc1.x *= 0.0625f; acc1.y *= 0.0625f; acc1.z *= 0.0625f; acc1.w *= 0.0625f;
      acc2.x *= 0.0625f; acc2.y *= 0.0625f; acc2.z *= 0.0625f; acc2.w *= 0.0625f;
      acc3.x *= 0.0625f; acc3.y *= 0.0625f; acc3.z *= 0.0625f; acc3.w *= 0.0625f;
      *reinterpret_cast<float4*>(&sc[0][s0]) = acc0;
      *reinterpret_cast<float4*>(&sc[1][s0]) = acc1;
      *reinterpret_cast<float4*>(&sc[2][s0]) = acc2;
      *reinterpret_cast<float4*>(&sc[3][s0]) = acc3;
    }
    __syncthreads();

    // wave r: pull its row into registers (lane-stride 4B, conflict-free)
    float srow[32];
#pragma unroll
    for (int j = 0; j < 32; ++j) {
      if (j * 64 < n) {                       // wave-uniform -> scalar branch
        const int s = lane + j * 64;
        const float v = sc[wave][s];
        srow[j] = (s < n) ? v : -1e30f;       // mask causal tail within chunk
      }
    }

    // max reduce
    float mx = -1e30f;
#pragma unroll
    for (int j = 0; j < 32; ++j)
      if (j * 64 < n) mx = fmaxf(mx, srow[j]);
#pragma unroll
    for (int m = 32; m >= 1; m >>= 1) mx = fmaxf(mx, __shfl_xor(mx, m, 64));

    // Newton on f(tau) = sum max(z-tau,0)^2 - 1 (convex, decreasing).
    // tau0 = mx-1 gives f>=0; iterates increase monotonically to tau*.
    // Break on function value: s2-1 < 1e-5 bounds the weight error at 1e-5.
    float tau = mx - 1.0f;
#pragma unroll 1
    for (int it = 0; it < 16; ++it) {
      float s1 = 0.f, s2 = 0.f;
#pragma unroll
      for (int j = 0; j < 32; ++j) {
        if (j * 64 < n) {
          const float u = fmaxf(srow[j] - tau, 0.f);
          s1 += u;
          s2 = fmaf(u, u, s2);
        }
      }
#pragma unroll
      for (int m = 32; m >= 1; m >>= 1) {
        s1 += __shfl_xor(s1, m, 64);
        s2 += __shfl_xor(s2, m, 64);
      }
      if (s2 - 1.0f < 1e-5f) break;  // wave-uniform (s2 fully reduced)
      tau += (s2 - 1.0f) / fmaxf(2.f * s1, 1e-12f);
    }
    tau = fminf(tau, mx - 1e-8f);

    // accumulate weights for this head
#pragma unroll
    for (int j = 0; j < 32; ++j) {
      if (j * 64 < n) {
        const float u = fmaxf(srow[j] - tau, 0.f);
        wacc[j] = fmaf(u, u, wacc[j]);
      }
    }
  }
  __syncthreads();  // sc free for reuse as wsum

  // dump register weights to LDS (full row; untouched chunks are zero)
#pragma unroll
  for (int j = 0; j < 32; ++j) sc[wave][lane + j * 64] = wacc[j];
  __syncthreads();

  // weights_avg: coalesced float4 stores, full T row (zeros past diagonal required)
  for (int i4 = tid; i4 < TQ_ * T_ / 4; i4 += 256) {
    const int r = i4 >> 9;                 // / (T_/4)
    const int c4 = i4 & 511;
    float4 w = reinterpret_cast<const float4*>(&sc[r][0])[c4];
    w.x *= 0.125f; w.y *= 0.125f; w.z *= 0.125f; w.w *= 0.125f;
    reinterpret_cast<float4*>(&wavg[(size_t)(b * T_ + t0 + r) * T_])[c4] = w;
  }

  // PV: attn_out[t0+r][d] = 0.125 * sum_s wsum[r][s] * Vc[s][d]
  {
    const int sg = tid >> 6, dd = tid & 63;
    float acc0 = 0.f, acc1 = 0.f, acc2 = 0.f, acc3 = 0.f;
    for (int s = sg; s < nS; s += 4) {
      const float v = Vc[(size_t)(b * T_ + s) * DK_ + dd];
      acc0 += sc[0][s] * v;
      acc1 += sc[1][s] * v;
      acc2 += sc[2][s] * v;
      acc3 += sc[3][s] * v;
    }
    part[sg][0][dd] = acc0;
    part[sg][1][dd] = acc1;
    part[sg][2][dd] = acc2;
    part[sg][3][dd] = acc3;
  }
  __syncthreads();
  {
    const int r = tid >> 6, dd = tid & 63;
    const float o = (part[0][r][dd] + part[1][r][dd] + part[2][r][dd] + part[3][r][dd]) * 0.125f;
    attn_out[(size_t)(b * T_ + t0 + r) * DK_ + dd] = o;
  }
}

extern "C" void kernel_launch(void* const* d_in, const int* in_sizes, int n_in,
                              void* d_out, int out_size, void* d_ws, size_t ws_size,
                              hipStream_t stream)
{
  const float* x  = (const float*)d_in[0];
  const float* Wq = (const float*)d_in[1];
  const float* bq = (const float*)d_in[2];
  const float* Wk = (const float*)d_in[3];
  const float* bk = (const float*)d_in[4];
  const float* Wv = (const float*)d_in[5];
  const float* bv = (const float*)d_in[6];
  const float* Wo = (const float*)d_in[7];
  const float* bo = (const float*)d_in[8];
  float* out = (float*)d_out;
  float* ws  = (float*)d_ws;

  float* Q  = ws;                        // [M,512]
  float* Kt = Q + (size_t)M_ * D_;       // [512,M]
  float* V  = Kt + (size_t)D_ * M_;      // [M,512]
  float* Vc = V + (size_t)M_ * D_;       // [M,64]
  float* AO = Vc + (size_t)M_ * DK_;     // [M,64]

  float* out1 = out;                    // [B,T,D]
  float* wavg = out + (size_t)M_ * D_;  // [B,T,T]

  const dim3 gp(D_ / 64, M_ / 64);  // (8, 64)
  gemm_bias_kernel <<<gp, 256, 0, stream>>>(x, Wq, bq, Q,  M_, D_, D_);
  gemm_bias_kernelT<<<gp, 256, 0, stream>>>(x, Wk, bk, Kt, M_, D_, D_);
  gemm_bias_kernel <<<gp, 256, 0, stream>>>(x, Wv, bv, V,  M_, D_, D_);
  vcombine_kernel<<<(M_ * DK_ + 255) / 256, 256, 0, stream>>>(V, Vc);
  attn_kernel<<<B_ * NT_, 256, 0, stream>>>(Q, Kt, Vc, wavg, AO);
  gemm_bias_kernel<<<gp, 256, 0, stream>>>(AO, Wo, bo, out1, M_, D_, DK_);
}